// Round 5
// baseline (105.672 us; speedup 1.0000x reference)
//
#include <hip/hip_runtime.h>
#include <hip/hip_bf16.h>

// CorrelationNetwork — single fused kernel for MI355X (gfx950), round 9.
// R8 bench failed with "MI355X container failed twice" = infra-level
// acquisition failure (kernel verdicts report passed:false + pytest error).
// Kernel re-audited: bounds/LDS(70.6KB)/occupancy/indexing all check out.
// Resubmitting R8 unchanged (dead var removed).
// Theory: total = ~73us invariant harness overhead + kernel. This removes
// setup_kernel (~6-10us + launch gap) and the 16MB AiP/Aj HBM round-trip:
// per block (b, ih) prepass computes Aj(64)+Ai(32) rows block-locally into
// the proven pad-132 LDS layout (W1 cached in 64 VGPRs, setup's exact fmaf
// chains -> bit-identical); W2 frags pulled straight from global f32 W2
// with manual RNE->bf16 (bit-identical to old W2T path); ajr extraction +
// 16-tile MFMA loop verbatim R7. Workspace unused. Softmax in block 0.

typedef __bf16 bf16x8 __attribute__((ext_vector_type(8)));
typedef float f32x4 __attribute__((ext_vector_type(4)));

__global__ __launch_bounds__(512, 2) void fused_kernel(
    const float* __restrict__ af, const float* __restrict__ W1,
    const float* __restrict__ b1, const float* __restrict__ W2,
    const float* __restrict__ b2, const float* __restrict__ w3,
    const float* __restrict__ b3, const float* __restrict__ mw,
    float* __restrict__ out)
{
  __shared__ __align__(16) float fl[64 * 64];      // af[b][n][0..63], 16 KB
  __shared__ __align__(16) float AjF[64 * 132];    // 33.8 KB, pad-132
  __shared__ __align__(16) float AiF[32 * 132];    // 16.9 KB
  __shared__ float b2s[128], w3s[128];
  __shared__ float part[2][2][128];                // [tile&1][wm][row]

  const int tid  = threadIdx.x;
  const int lane = tid & 63;
  const int wave = tid >> 6;            // 0..7
  const int c = lane & 15, g = lane >> 4;
  const int wm = wave & 1;              // w2col half (64 cols)
  const int wn = wave >> 1;             // row quarter (32 rows)

  const int blk = blockIdx.x;
  const int b   = blk >> 1;             // 0..127
  const int ih  = blk & 1;              // i-half (16 i-pairs)
  const int ip0 = ih << 4;

  // ---- softmax of mixing weights (block 0, wave 0 only)
  if (blk == 0 && tid < 64) {
    float v = mw[tid];
    float m = v;
    for (int off = 32; off > 0; off >>= 1) m = fmaxf(m, __shfl_xor(m, off));
    float e = expf(v - m);
    float s = e;
    for (int off = 32; off > 0; off >>= 1) s += __shfl_xor(s, off);
    out[128 * 64 * 64 + tid] = e / s;
  }

  // ---- stage fl = af[b][0..63][0..63] (16 KB) + b2s/w3s, coalesced
  {
    const float4* srcQ = (const float4*)(af + (b << 13));
#pragma unroll
    for (int p = 0; p < 2; ++p) {
      const int idx = (p << 9) + tid;            // 0..1023 float4s
      const int n = idx >> 4, e = idx & 15;
      *(float4*)&fl[(n << 6) + (e << 2)] = srcQ[(n << 5) + e];
    }
    if (tid < 128) b2s[tid] = b2[tid];
    else if (tid < 256) w3s[tid - 128] = w3[tid - 128];
  }

  // ---- W2 fragments straight from global f32 (L2-resident, coalesced across
  // the wave's c within each line), manual RNE -> bf16 (bit-identical to the
  // old W2T path). Lane (c,g) frag element e: m = wm*64+mt*16+c,
  // k = kt*32+g*8+e, value = W2[k][m].
  bf16x8 w2r[4][4];
  {
    union U { unsigned short s; __bf16 h; };
#pragma unroll
    for (int mt = 0; mt < 4; ++mt)
#pragma unroll
      for (int kt = 0; kt < 4; ++kt) {
        const float* wp = W2 + (((kt << 5) + (g << 3)) << 7) +
                          (wm << 6) + (mt << 4) + c;
#pragma unroll
        for (int e = 0; e < 8; ++e) {
          unsigned u = __float_as_uint(wp[e << 7]);
          u += 0x7fffu + ((u >> 16) & 1u);
          U cv; cv.s = (unsigned short)(u >> 16);
          w2r[mt][kt][e] = cv.h;
        }
      }
  }

  const int h = tid & 127;
  const int q = tid >> 7;                        // 0..3
  const float b1h = b1[h];
  const float bias3 = b3[0];

  __syncthreads();                               // fl/b2s/w3s ready

  // ---- prepass (setup's exact fmaf chains, W1 register-cached).
  // Thread (h,q): Aj rows q*16..q*16+15 (W1[64:]), Ai rows q*8..q*8+7 (W1[:64]).
  {
    float w1c[64];
    // Aj half: W1 rows 64..127, column h
#pragma unroll
    for (int f = 0; f < 64; ++f) w1c[f] = W1[((64 + f) << 7) + h];
#pragma unroll
    for (int qd = 0; qd < 4; ++qd) {
      const int r0 = (q << 4) + (qd << 2);
      float a0 = 0.f, a1 = 0.f, a2 = 0.f, a3 = 0.f;
#pragma unroll
      for (int fq = 0; fq < 16; ++fq) {
        const float w0  = w1c[fq * 4 + 0];
        const float w1v = w1c[fq * 4 + 1];
        const float w2v = w1c[fq * 4 + 2];
        const float w3v = w1c[fq * 4 + 3];
        const float4 f0 = *(const float4*)&fl[((r0 + 0) << 6) + (fq << 2)];
        const float4 f1 = *(const float4*)&fl[((r0 + 1) << 6) + (fq << 2)];
        const float4 f2 = *(const float4*)&fl[((r0 + 2) << 6) + (fq << 2)];
        const float4 f3 = *(const float4*)&fl[((r0 + 3) << 6) + (fq << 2)];
        a0 = fmaf(f0.x, w0, fmaf(f0.y, w1v, fmaf(f0.z, w2v, fmaf(f0.w, w3v, a0))));
        a1 = fmaf(f1.x, w0, fmaf(f1.y, w1v, fmaf(f1.z, w2v, fmaf(f1.w, w3v, a1))));
        a2 = fmaf(f2.x, w0, fmaf(f2.y, w1v, fmaf(f2.z, w2v, fmaf(f2.w, w3v, a2))));
        a3 = fmaf(f3.x, w0, fmaf(f3.y, w1v, fmaf(f3.z, w2v, fmaf(f3.w, w3v, a3))));
      }
      AjF[(r0 + 0) * 132 + h] = a0;
      AjF[(r0 + 1) * 132 + h] = a1;
      AjF[(r0 + 2) * 132 + h] = a2;
      AjF[(r0 + 3) * 132 + h] = a3;
    }
    // Ai half: W1 rows 0..63, +b1; fl row = ih*32 + local row
#pragma unroll
    for (int f = 0; f < 64; ++f) w1c[f] = W1[(f << 7) + h];
#pragma unroll
    for (int qd = 0; qd < 2; ++qd) {
      const int r0 = (q << 3) + (qd << 2);
      const int fr = (ih << 5) + r0;
      float a0 = 0.f, a1 = 0.f, a2 = 0.f, a3 = 0.f;
#pragma unroll
      for (int fq = 0; fq < 16; ++fq) {
        const float w0  = w1c[fq * 4 + 0];
        const float w1v = w1c[fq * 4 + 1];
        const float w2v = w1c[fq * 4 + 2];
        const float w3v = w1c[fq * 4 + 3];
        const float4 f0 = *(const float4*)&fl[((fr + 0) << 6) + (fq << 2)];
        const float4 f1 = *(const float4*)&fl[((fr + 1) << 6) + (fq << 2)];
        const float4 f2 = *(const float4*)&fl[((fr + 2) << 6) + (fq << 2)];
        const float4 f3 = *(const float4*)&fl[((fr + 3) << 6) + (fq << 2)];
        a0 = fmaf(f0.x, w0, fmaf(f0.y, w1v, fmaf(f0.z, w2v, fmaf(f0.w, w3v, a0))));
        a1 = fmaf(f1.x, w0, fmaf(f1.y, w1v, fmaf(f1.z, w2v, fmaf(f1.w, w3v, a1))));
        a2 = fmaf(f2.x, w0, fmaf(f2.y, w1v, fmaf(f2.z, w2v, fmaf(f2.w, w3v, a2))));
        a3 = fmaf(f3.x, w0, fmaf(f3.y, w1v, fmaf(f3.z, w2v, fmaf(f3.w, w3v, a3))));
      }
      AiF[(r0 + 0) * 132 + h] = a0 + b1h;
      AiF[(r0 + 1) * 132 + h] = a1 + b1h;
      AiF[(r0 + 2) * 132 + h] = a2 + b1h;
      AiF[(r0 + 3) * 132 + h] = a3 + b1h;
    }
  }

  __syncthreads();                               // AjF/AiF ready

  // ---- tile-invariant Aj fragments -> registers (verbatim R7)
  f32x4 ajr[4][2][2];
#pragma unroll
  for (int kt = 0; kt < 4; ++kt)
#pragma unroll
    for (int tn = 0; tn < 2; ++tn) {
      const int j = ((wn << 5) + (tn << 4) + c) & 63;
      const float* ajb = &AjF[j * 132 + (g << 3) + (kt << 5)];
      ajr[kt][tn][0] = *(const f32x4*)(ajb);
      ajr[kt][tn][1] = *(const f32x4*)(ajb + 4);
    }

  const int i_sel = wn >> 1;                     // row>=64 -> second i of pair

  for (int t = 0; t < 16; ++t) {
    const float* aib = &AiF[((t << 1) + i_sel) * 132 + (g << 3)];

    f32x4 acc[4][2];
#pragma unroll
    for (int mt = 0; mt < 4; ++mt) {
      const f32x4 bv = *(const f32x4*)&b2s[(wm << 6) + (mt << 4) + (g << 2)];
      acc[mt][0] = bv;
      acc[mt][1] = bv;
    }

#pragma unroll
    for (int kt = 0; kt < 4; ++kt) {
      const f32x4 a0 = *(const f32x4*)(aib + (kt << 5));
      const f32x4 a1 = *(const f32x4*)(aib + (kt << 5) + 4);
      bf16x8 hv[2];
#pragma unroll
      for (int tn = 0; tn < 2; ++tn) {
        const f32x4 h0  = a0 + ajr[kt][tn][0];
        const f32x4 h1v = a1 + ajr[kt][tn][1];
#pragma unroll
        for (int e = 0; e < 4; ++e) {
          hv[tn][e]     = (__bf16)fmaxf(h0[e], 0.f);
          hv[tn][e + 4] = (__bf16)fmaxf(h1v[e], 0.f);
        }
      }
#pragma unroll
      for (int mt = 0; mt < 4; ++mt)
#pragma unroll
        for (int tn = 0; tn < 2; ++tn)
          acc[mt][tn] = __builtin_amdgcn_mfma_f32_16x16x32_bf16(
              w2r[mt][kt], hv[tn], acc[mt][tn], 0, 0, 0);
    }

    float s0 = 0.f, s1 = 0.f;
#pragma unroll
    for (int mt = 0; mt < 4; ++mt) {
      const f32x4 wv3 = *(const f32x4*)&w3s[(wm << 6) + (mt << 4) + (g << 2)];
#pragma unroll
      for (int p = 0; p < 4; ++p) {
        s0 = fmaf(fmaxf(acc[mt][0][p], 0.f), wv3[p], s0);
        s1 = fmaf(fmaxf(acc[mt][1][p], 0.f), wv3[p], s1);
      }
    }
    s0 += __shfl_xor(s0, 16);
    s0 += __shfl_xor(s0, 32);
    s1 += __shfl_xor(s1, 16);
    s1 += __shfl_xor(s1, 32);

    const int pb = t & 1;
    if (g == 0) {                                // 16 lanes, conflict-free
      part[pb][wm][(wn << 5) + c]      = s0;
      part[pb][wm][(wn << 5) + 16 + c] = s1;
    }

    __syncthreads();                             // one barrier per tile

    if (tid < 128) {
      const float v = part[pb][0][tid] + part[pb][1][tid] + bias3;
      out[(b << 12) + ((ip0 + t) << 7) + tid] = 1.f / (1.f + __expf(-v));
    }
  }
}

extern "C" void kernel_launch(void* const* d_in, const int* in_sizes, int n_in,
                              void* d_out, int out_size, void* d_ws,
                              size_t ws_size, hipStream_t stream)
{
  const float* af = (const float*)d_in[0];   // (128,64,128)
  const float* W1 = (const float*)d_in[1];   // (128,128)
  const float* b1 = (const float*)d_in[2];   // (128,)
  const float* W2 = (const float*)d_in[3];   // (128,128)
  const float* b2 = (const float*)d_in[4];   // (128,)
  const float* w3 = (const float*)d_in[5];   // (128,)
  const float* b3 = (const float*)d_in[6];   // (1,)
  const float* mw = (const float*)d_in[7];   // (64,)
  float* out = (float*)d_out;                // 524288 corr + 64 weights

  (void)d_ws; (void)ws_size;
  // one kernel: 256 blocks (1/CU), block = (b, i-half), 16 tiles each
  fused_kernel<<<256, 512, 0, stream>>>(af, W1, b1, W2, b2, w3, b3, mw, out);
}